// Round 5
// baseline (119.568 us; speedup 1.0000x reference)
//
#include <hip/hip_runtime.h>

// SASA plain 3-kernel pipeline, R10: pixel-pair online-softmax p2 + cvt_pk bf16.
// B=2, CIN=192, HW=3136, 6 heads x d=32, 7x7 window.
// Cost model: dur_us = kernels + 2x256MiB ws-poison fills (~42.5us each, HBM-bound
// -> fill time is the container-health gauge).
// History: R6=110.2 | R9 (DPP qsum + deferred inv) = 105.6 (fills 42.4).
// Pipe model (R9): p2 LDS-byte-bound: 3136 B/thread LDS reads -> ~14.4Kcyc/CU
// (~6us) vs VALU ~2.3us. p1 VALU-bound (~3us, pack2-heavy staging).
// R10 changes:
//  (a) p2: 2 adjacent pixels per thread (pxA even, pxB=pxA+1), 128-thr blocks.
//      Windows share 6/7 columns -> read the 8-column union once per ky:
//      8 chunks vs 14 per (ky,K/V) = 0.57x LDS bytes, same FMA count.
//      Online softmax (running m,s; rescale acc) fuses QK+softmax+PV per ky.
//      LDS layout/stride 34 UNCHANGED (measured-good banks; even pxA keeps
//      float2 reads 8B-aligned; min 2 accesses/bank per quarter-wave).
//  (b) pack2 -> v_cvt_pk_bf16_f32 (1 instr vs ~7, RTNE = bit-identical);
//      p1 epilogue pair-packed; p2 output packed to one uint4 store.
//
// ws layout (bytes):
//   QKV  [6272][576] bf16 @ 0        q ch 0-191 | k 192-383 | v 384-575
//   OACT [6272][192] bf16 @ 7225344  attention out = proj B-operand

#define HW    3136
#define WIMG  56
#define CIN   192
#define QKVLD 576
#define SMEM_BYTES 53312

using short8 = __attribute__((ext_vector_type(8))) short;
using f32x4  = __attribute__((ext_vector_type(4))) float;

__device__ __forceinline__ unsigned short f2bf(float f) {
    union { float f; unsigned u; } v; v.f = f;
    unsigned r = v.u + 0x7fffu + ((v.u >> 16) & 1u);
    return (unsigned short)(r >> 16);
}
// packed RTNE f32x2 -> bf16x2, single HW instruction (lo = a, hi = b)
__device__ __forceinline__ unsigned pack2(float a, float b) {
    unsigned r;
    asm("v_cvt_pk_bf16_f32 %0, %1, %2" : "=v"(r) : "v"(a), "v"(b));
    return r;
}
__device__ __forceinline__ float bflo(unsigned u) {
    union { unsigned u; float f; } v; v.u = u << 16; return v.f;
}
__device__ __forceinline__ float bfhi(unsigned u) {
    union { unsigned u; float f; } v; v.u = u & 0xffff0000u; return v.f;
}
// quad-of-4 butterfly sum via DPP quad_perm (VALU pipe, not ds_swizzle/LDS).
__device__ __forceinline__ float qsum4(float s) {
    union { float f; int i; } u, t;
    u.f = s;
    t.i = __builtin_amdgcn_update_dpp(0, u.i, 0xB1, 0xF, 0xF, true); // xor 1
    u.f += t.f;
    t.i = __builtin_amdgcn_update_dpp(0, u.i, 0x4E, 0xF, 0xF, true); // xor 2
    u.f += t.f;
    return u.f;
}

// ======================= Phase 1: QKV GEMM tile =============================
// t in [0,882): mt = t%98 (64-pixel strip over b,p), nt = t/98 (64 of 576 out ch).
__global__ __launch_bounds__(256) void k_p1(
    const float* __restrict__ x, const float* __restrict__ wq,
    const float* __restrict__ wk, const float* __restrict__ wv,
    unsigned short* __restrict__ qkv)
{
    extern __shared__ char smem[];
    unsigned short* As  = (unsigned short*)smem;     // 64 x 200 ushorts
    unsigned short* Bs  = As + 64 * 200;
    unsigned*       Asw = (unsigned*)smem;           // dword view, row stride 100
    unsigned*       Bsw = (unsigned*)(smem + 25600);

    const int tid = threadIdx.x;
    const int lane = tid & 63, wave = tid >> 6;
    const int l15  = lane & 15, quad = lane >> 4;
    const int wm   = (wave & 1) * 32, wn = (wave >> 1) * 32;

    const int t = blockIdx.x;
    const int mt = t % 98, nt = t / 98;
    const int m0 = mt * 64, n0 = nt * 64;
    const float* Wp = (nt < 3) ? (wq + (size_t)n0 * CIN)
                    : (nt < 6) ? (wk + (size_t)(n0 - 192) * CIN)
                               : (wv + (size_t)(n0 - 384) * CIN);

    #pragma unroll
    for (int i = 0; i < 6; ++i) {
        int u = tid + 256 * i;
        int pq = u & 15, c2 = u >> 4;            // pq: p-quad 0..15, c2: 0..95
        int pp = m0 + pq * 4;
        int bb = (pp >= HW) ? 1 : 0;
        const float* src = x + ((size_t)(bb * CIN + c2 * 2)) * HW + (pp - bb * HW);
        float4 f0 = *(const float4*)src;          // c = c2*2,   p..p+3
        float4 f1 = *(const float4*)(src + HW);   // c = c2*2+1, p..p+3
        Asw[(pq * 4 + 0) * 100 + c2] = pack2(f0.x, f1.x);
        Asw[(pq * 4 + 1) * 100 + c2] = pack2(f0.y, f1.y);
        Asw[(pq * 4 + 2) * 100 + c2] = pack2(f0.z, f1.z);
        Asw[(pq * 4 + 3) * 100 + c2] = pack2(f0.w, f1.w);
    }
    {
        int o = tid >> 2, c4 = tid & 3;
        #pragma unroll
        for (int i = 0; i < 12; ++i) {
            int cq = c4 + 4 * i;                 // 0..47
            float4 w = *(const float4*)(Wp + (size_t)o * CIN + cq * 4);
            uint2 d; d.x = pack2(w.x, w.y); d.y = pack2(w.z, w.w);
            *(uint2*)(Bsw + o * 100 + cq * 2) = d;
        }
    }
    __syncthreads();

    f32x4 acc[2][2] = {};
    const unsigned short* pa0 = As + (wm + l15) * 200 + quad * 8;
    const unsigned short* pb0 = Bs + (wn + l15) * 200 + quad * 8;
    #pragma unroll
    for (int s = 0; s < 6; ++s) {
        short8 a0 = *(const short8*)(pa0 + s * 32);
        short8 a1 = *(const short8*)(pa0 + 16 * 200 + s * 32);
        short8 b0 = *(const short8*)(pb0 + s * 32);
        short8 b1 = *(const short8*)(pb0 + 16 * 200 + s * 32);
        acc[0][0] = __builtin_amdgcn_mfma_f32_16x16x32_bf16(a0, b0, acc[0][0], 0, 0, 0);
        acc[0][1] = __builtin_amdgcn_mfma_f32_16x16x32_bf16(a0, b1, acc[0][1], 0, 0, 0);
        acc[1][0] = __builtin_amdgcn_mfma_f32_16x16x32_bf16(a1, b0, acc[1][0], 0, 0, 0);
        acc[1][1] = __builtin_amdgcn_mfma_f32_16x16x32_bf16(a1, b1, acc[1][1], 0, 0, 0);
    }

    const int gm = m0 + wm + quad * 4;   // global pixel row
    const int gn = n0 + wn + l15;        // output channel (0..575)
    #pragma unroll
    for (int ti = 0; ti < 2; ++ti)
        #pragma unroll
        for (int tj = 0; tj < 2; ++tj)
            #pragma unroll
            for (int rr = 0; rr < 4; rr += 2) {
                unsigned r = pack2(acc[ti][tj][rr], acc[ti][tj][rr + 1]);
                qkv[(size_t)(gm + ti * 16 + rr) * QKVLD + (gn + tj * 16)] =
                    (unsigned short)r;
                qkv[(size_t)(gm + ti * 16 + rr + 1) * QKVLD + (gn + tj * 16)] =
                    (unsigned short)(r >> 16);
            }
}

// ======================= Phase 2: windowed attention ========================
// t in [0,588): 49 8x8-pixel tiles x 12 (b,h). 128 threads: 4/pixel-pair
// (d split 4x8ch), each thread computes 2 adjacent pixels (pxA even, pxB=pxA+1)
// with online softmax; K/V window-union columns read once per ky.
__global__ __launch_bounds__(128) void k_p2(
    const unsigned short* __restrict__ qkv, const float* __restrict__ pos,
    unsigned short* __restrict__ oact)
{
    extern __shared__ char smem[];
    float* kbuf = (float*)smem;          // [196 px][32 ch] stride 34 floats
    float* vbuf = kbuf + 6664;

    const int tid = threadIdx.x;
    const int t = blockIdx.x;
    const int tz = t / 49, r49 = t - tz * 49;
    const int ty = r49 / 7, tx = r49 - ty * 7;
    const int bq = tz / 6, h = tz - bq * 6;
    const int y0 = ty * 8 - 3, x0 = tx * 8 - 3;

    const int sub = tid & 3, pix2 = tid >> 2;        // pix2 0..31
    const int py = pix2 >> 2, pxA = (pix2 & 3) * 2;  // pxA in {0,2,4,6}
    const int y = ty * 8 + py, xA = tx * 8 + pxA;
    const int pA = y * WIMG + xA;                    // pixel B = pA+1

    // Q for both pixels + pos, hoisted above staging (latency overlaps stores)
    uint4 qva = *(const uint4*)(qkv + (size_t)(bq * HW + pA) * QKVLD + h * 32 + sub * 8);
    uint4 qvb = *(const uint4*)(qkv + (size_t)(bq * HW + pA + 1) * QKVLD + h * 32 + sub * 8);
    float posr[13];
    #pragma unroll
    for (int i = 0; i < 13; ++i) posr[i] = pos[i];

    // unified K+V staging: 1568 uint4 units = 196 px * (4 k + 4 v)
    #pragma unroll
    for (int i = 0; i < 13; ++i) {
        int u = tid + 128 * i;
        if (u < 1568) {
            int pp = u >> 3, uu = u & 7;
            int part = uu >> 2, sub8 = uu & 3;       // part 0=k, 1=v
            int ppy = pp / 14, ppx = pp - ppy * 14;
            int gy = y0 + ppy, gx = x0 + ppx;
            float f0=0,f1=0,f2=0,f3=0,f4=0,f5=0,f6=0,f7=0;
            if ((unsigned)gy < 56u && (unsigned)gx < 56u) {
                uint4 rv = *(const uint4*)(qkv +
                    (size_t)(bq * HW + gy * WIMG + gx) * QKVLD +
                    192 + part * 192 + h * 32 + sub8 * 8);
                f0=bflo(rv.x); f1=bfhi(rv.x); f2=bflo(rv.y); f3=bfhi(rv.y);
                f4=bflo(rv.z); f5=bfhi(rv.z); f6=bflo(rv.w); f7=bfhi(rv.w);
            }
            float* dst = (part ? vbuf : kbuf) + pp * 34 + sub8 * 8;
            *(float2*)(dst + 0) = make_float2(f0, f1);
            *(float2*)(dst + 2) = make_float2(f2, f3);
            *(float2*)(dst + 4) = make_float2(f4, f5);
            *(float2*)(dst + 6) = make_float2(f6, f7);
        }
    }
    __syncthreads();

    float qa[8], qb[8];
    qa[0]=bflo(qva.x); qa[1]=bfhi(qva.x); qa[2]=bflo(qva.y); qa[3]=bfhi(qva.y);
    qa[4]=bflo(qva.z); qa[5]=bfhi(qva.z); qa[6]=bflo(qva.w); qa[7]=bfhi(qva.w);
    qb[0]=bflo(qvb.x); qb[1]=bfhi(qvb.x); qb[2]=bflo(qvb.y); qb[3]=bfhi(qvb.y);
    qb[4]=bflo(qvb.z); qb[5]=bfhi(qvb.z); qb[6]=bflo(qvb.w); qb[7]=bfhi(qvb.w);

    float accA[8] = {0,0,0,0,0,0,0,0}, accB[8] = {0,0,0,0,0,0,0,0};
    float mA = -1e30f, mB = -1e30f, sA = 0.f, sB = 0.f;

    #pragma unroll
    for (int ky = 0; ky < 7; ++ky) {
        const int rowo = ((py + ky) * 14 + pxA) * 34 + sub * 8;
        const float* rk = kbuf + rowo;
        float dA[7], dB[7];
        #pragma unroll
        for (int c = 0; c < 8; ++c) {               // union columns
            const float2* cp = (const float2*)(rk + c * 34);
            float2 c0 = cp[0], c1 = cp[1], c2 = cp[2], c3 = cp[3];
            if (c < 7) {
                float s = 0.f;
                s = fmaf(qa[0], c0.x, s); s = fmaf(qa[1], c0.y, s);
                s = fmaf(qa[2], c1.x, s); s = fmaf(qa[3], c1.y, s);
                s = fmaf(qa[4], c2.x, s); s = fmaf(qa[5], c2.y, s);
                s = fmaf(qa[6], c3.x, s); s = fmaf(qa[7], c3.y, s);
                dA[c] = s;
            }
            if (c > 0) {
                float s = 0.f;
                s = fmaf(qb[0], c0.x, s); s = fmaf(qb[1], c0.y, s);
                s = fmaf(qb[2], c1.x, s); s = fmaf(qb[3], c1.y, s);
                s = fmaf(qb[4], c2.x, s); s = fmaf(qb[5], c2.y, s);
                s = fmaf(qb[6], c3.x, s); s = fmaf(qb[7], c3.y, s);
                dB[c - 1] = s;
            }
        }
        float lA[7], lB[7];
        #pragma unroll
        for (int c = 0; c < 7; ++c) {
            lA[c] = qsum4(dA[c]) + posr[ky + c];
            lB[c] = qsum4(dB[c]) + posr[ky + c];
        }
        float mAn = mA, mBn = mB;
        #pragma unroll
        for (int c = 0; c < 7; ++c) { mAn = fmaxf(mAn, lA[c]); mBn = fmaxf(mBn, lB[c]); }
        const float scA = __expf(mA - mAn), scB = __expf(mB - mBn);
        mA = mAn; mB = mBn;
        sA *= scA; sB *= scB;
        float pwA[7], pwB[7];
        #pragma unroll
        for (int c = 0; c < 7; ++c) {
            pwA[c] = __expf(lA[c] - mA); sA += pwA[c];
            pwB[c] = __expf(lB[c] - mB); sB += pwB[c];
        }
        #pragma unroll
        for (int j = 0; j < 8; ++j) { accA[j] *= scA; accB[j] *= scB; }
        const float* rv = vbuf + rowo;
        #pragma unroll
        for (int c = 0; c < 8; ++c) {
            const float2* vp = (const float2*)(rv + c * 34);
            float2 v0 = vp[0], v1 = vp[1], v2 = vp[2], v3 = vp[3];
            if (c < 7) {
                const float w = pwA[c];
                accA[0]=fmaf(w,v0.x,accA[0]); accA[1]=fmaf(w,v0.y,accA[1]);
                accA[2]=fmaf(w,v1.x,accA[2]); accA[3]=fmaf(w,v1.y,accA[3]);
                accA[4]=fmaf(w,v2.x,accA[4]); accA[5]=fmaf(w,v2.y,accA[5]);
                accA[6]=fmaf(w,v3.x,accA[6]); accA[7]=fmaf(w,v3.y,accA[7]);
            }
            if (c > 0) {
                const float w = pwB[c - 1];
                accB[0]=fmaf(w,v0.x,accB[0]); accB[1]=fmaf(w,v0.y,accB[1]);
                accB[2]=fmaf(w,v1.x,accB[2]); accB[3]=fmaf(w,v1.y,accB[3]);
                accB[4]=fmaf(w,v2.x,accB[4]); accB[5]=fmaf(w,v2.y,accB[5]);
                accB[6]=fmaf(w,v3.x,accB[6]); accB[7]=fmaf(w,v3.y,accB[7]);
            }
        }
    }

    const float invA = 1.f / sA, invB = 1.f / sB;
    uint4 oA, oB;
    oA.x = pack2(accA[0]*invA, accA[1]*invA);
    oA.y = pack2(accA[2]*invA, accA[3]*invA);
    oA.z = pack2(accA[4]*invA, accA[5]*invA);
    oA.w = pack2(accA[6]*invA, accA[7]*invA);
    oB.x = pack2(accB[0]*invB, accB[1]*invB);
    oB.y = pack2(accB[2]*invB, accB[3]*invB);
    oB.z = pack2(accB[4]*invB, accB[5]*invB);
    oB.w = pack2(accB[6]*invB, accB[7]*invB);
    *(uint4*)(oact + (size_t)(bq * HW + pA) * CIN + h * 32 + sub * 8)     = oA;
    *(uint4*)(oact + (size_t)(bq * HW + pA + 1) * CIN + h * 32 + sub * 8) = oB;
}

// ======================= Phase 3: projection tile ===========================
// t in [0,294): mt = t%3 (64 out ch), pt = t/3 (64-pixel strip).
__global__ __launch_bounds__(256) void k_p3(
    const float* __restrict__ wproj, const unsigned short* __restrict__ oact,
    float* __restrict__ out)
{
    extern __shared__ char smem[];
    unsigned short* As  = (unsigned short*)smem;
    unsigned short* Bs  = As + 64 * 200;
    unsigned*       Asw = (unsigned*)smem;

    const int tid = threadIdx.x;
    const int lane = tid & 63, wave = tid >> 6;
    const int l15  = lane & 15, quad = lane >> 4;
    const int wm   = (wave & 1) * 32, wn = (wave >> 1) * 32;

    const int t = blockIdx.x;
    const int mt = t % 3, pt = t / 3;
    {
        int o = tid >> 2, c4 = tid & 3;
        #pragma unroll
        for (int i = 0; i < 12; ++i) {
            int cq = c4 + 4 * i;
            float4 w = *(const float4*)(wproj + (size_t)(mt * 64 + o) * CIN + cq * 4);
            uint2 d; d.x = pack2(w.x, w.y); d.y = pack2(w.z, w.w);
            *(uint2*)(Asw + o * 100 + cq * 2) = d;
        }
    }
    {
        int rw = tid >> 2, s4 = tid & 3;
        #pragma unroll
        for (int i = 0; i < 6; ++i) {
            int seg = s4 + 4 * i;               // 0..23
            uint4 dv = *(const uint4*)(oact + (size_t)(pt * 64 + rw) * CIN + seg * 8);
            *(uint4*)(Bs + rw * 200 + seg * 8) = dv;
        }
    }
    __syncthreads();

    f32x4 acc[2][2] = {};
    const unsigned short* pa0 = As + (wm + l15) * 200 + quad * 8;
    const unsigned short* pb0 = Bs + (wn + l15) * 200 + quad * 8;
    #pragma unroll
    for (int s = 0; s < 6; ++s) {
        short8 a0 = *(const short8*)(pa0 + s * 32);
        short8 a1 = *(const short8*)(pa0 + 16 * 200 + s * 32);
        short8 b0 = *(const short8*)(pb0 + s * 32);
        short8 b1 = *(const short8*)(pb0 + 16 * 200 + s * 32);
        acc[0][0] = __builtin_amdgcn_mfma_f32_16x16x32_bf16(a0, b0, acc[0][0], 0, 0, 0);
        acc[0][1] = __builtin_amdgcn_mfma_f32_16x16x32_bf16(a0, b1, acc[0][1], 0, 0, 0);
        acc[1][0] = __builtin_amdgcn_mfma_f32_16x16x32_bf16(a1, b0, acc[1][0], 0, 0, 0);
        acc[1][1] = __builtin_amdgcn_mfma_f32_16x16x32_bf16(a1, b1, acc[1][1], 0, 0, 0);
    }

    const int bb = (pt * 64 >= HW) ? 1 : 0;
    const int pl = pt * 64 - bb * HW + wn + l15;      // col = pixel within batch
    const int go = mt * 64 + wm + quad * 4;           // row = output channel
    float* Yb = out + (size_t)bb * (CIN * HW);
    #pragma unroll
    for (int ti = 0; ti < 2; ++ti)
        #pragma unroll
        for (int tj = 0; tj < 2; ++tj)
            #pragma unroll
            for (int rr = 0; rr < 4; ++rr)
                Yb[(size_t)(go + ti * 16 + rr) * HW + pl + tj * 16] = acc[ti][tj][rr];
}

// ---------------------------------------------------------------------------
extern "C" void kernel_launch(void* const* d_in, const int* in_sizes, int n_in,
                              void* d_out, int out_size, void* d_ws, size_t ws_size,
                              hipStream_t stream)
{
    const float* x     = (const float*)d_in[0];
    const float* wq    = (const float*)d_in[1];
    const float* wk    = (const float*)d_in[2];
    const float* wv    = (const float*)d_in[3];
    const float* pos   = (const float*)d_in[4];
    const float* wproj = (const float*)d_in[5];

    char* ws = (char*)d_ws;
    unsigned short* qkvp  = (unsigned short*)ws;
    unsigned short* oactp = (unsigned short*)(ws + 7225344);
    float*          outp  = (float*)d_out;

    k_p1<<<dim3(882), dim3(256), SMEM_BYTES, stream>>>(x, wq, wk, wv, qkvp);
    k_p2<<<dim3(588), dim3(128), SMEM_BYTES, stream>>>(qkvp, pos, oactp);
    k_p3<<<dim3(294), dim3(256), SMEM_BYTES, stream>>>(wproj, oactp, outp);
}

// Round 6
// 105.647 us; speedup vs baseline: 1.1318x; 1.1318x over previous
//
#include <hip/hip_runtime.h>

// SASA plain 3-kernel pipeline, R11: R9 anchor + cvt_pk + exp2-domain softmax.
// B=2, CIN=192, HW=3136, 6 heads x d=32, 7x7 window.
// Cost model: dur_us = kernels + 2x256MiB ws-poison fills (~42.5us each, HBM-bound
// -> fill time is the container-health gauge).
// History: R6=110.2 | R9=105.6 (DPP qsum + deferred inv; fills 42.4) |
//   R10 pixel-pair online-softmax = 119.6 FAILED (128thr x 53KB -> 1.5 waves/SIMD,
//   2x per-thread body; lesson: p2 changes must keep >=2 waves/SIMD) |
//   R8 isolates bf16-LDS(+hoist) at +7.4us real, cause unexplained -> LDS format
//   changes quarantined.
// R11 changes (all local, regime-preserving):
//  (a) pack2 -> v_cvt_pk_bf16_f32 single instr (validated bit-identical in R10).
//  (b) p2 softmax in exp2 domain: q,pos pre-scaled by log2e once; exp2f direct
//      (saves the hidden mul in each of 49 __expf).
//  (c) p1 epilogue pair-packed (8 cvt_pk vs 16 f2bf).
//
// ws layout (bytes):
//   QKV  [6272][576] bf16 @ 0        q ch 0-191 | k 192-383 | v 384-575
//   OACT [6272][192] bf16 @ 7225344  attention out = proj B-operand

#define HW    3136
#define WIMG  56
#define CIN   192
#define QKVLD 576
#define SMEM_BYTES 53312
#define LOG2E 1.44269504088896340736f

using short8 = __attribute__((ext_vector_type(8))) short;
using f32x4  = __attribute__((ext_vector_type(4))) float;

// packed RTNE f32x2 -> bf16x2, single HW instruction (lo = a, hi = b)
__device__ __forceinline__ unsigned pack2(float a, float b) {
    unsigned r;
    asm("v_cvt_pk_bf16_f32 %0, %1, %2" : "=v"(r) : "v"(a), "v"(b));
    return r;
}
__device__ __forceinline__ float bflo(unsigned u) {
    union { unsigned u; float f; } v; v.u = u << 16; return v.f;
}
__device__ __forceinline__ float bfhi(unsigned u) {
    union { unsigned u; float f; } v; v.u = u & 0xffff0000u; return v.f;
}
// quad-of-4 butterfly sum via DPP quad_perm (VALU pipe, not ds_swizzle/LDS).
__device__ __forceinline__ float qsum4(float s) {
    union { float f; int i; } u, t;
    u.f = s;
    t.i = __builtin_amdgcn_update_dpp(0, u.i, 0xB1, 0xF, 0xF, true); // xor 1
    u.f += t.f;
    t.i = __builtin_amdgcn_update_dpp(0, u.i, 0x4E, 0xF, 0xF, true); // xor 2
    u.f += t.f;
    return u.f;
}

// ======================= Phase 1: QKV GEMM tile =============================
// t in [0,882): mt = t%98 (64-pixel strip over b,p), nt = t/98 (64 of 576 out ch).
// A: transpose x[b][c][p] fp32 -> As[p][c] bf16 in staging. B: W rows -> bf16.
__global__ __launch_bounds__(256) void k_p1(
    const float* __restrict__ x, const float* __restrict__ wq,
    const float* __restrict__ wk, const float* __restrict__ wv,
    unsigned short* __restrict__ qkv)
{
    extern __shared__ char smem[];
    unsigned short* As  = (unsigned short*)smem;     // 64 x 200 ushorts
    unsigned short* Bs  = As + 64 * 200;
    unsigned*       Asw = (unsigned*)smem;           // dword view, row stride 100
    unsigned*       Bsw = (unsigned*)(smem + 25600);

    const int tid = threadIdx.x;
    const int lane = tid & 63, wave = tid >> 6;
    const int l15  = lane & 15, quad = lane >> 4;
    const int wm   = (wave & 1) * 32, wn = (wave >> 1) * 32;

    const int t = blockIdx.x;
    const int mt = t % 98, nt = t / 98;
    const int m0 = mt * 64, n0 = nt * 64;
    const float* Wp = (nt < 3) ? (wq + (size_t)n0 * CIN)
                    : (nt < 6) ? (wk + (size_t)(n0 - 192) * CIN)
                               : (wv + (size_t)(n0 - 384) * CIN);

    #pragma unroll
    for (int i = 0; i < 6; ++i) {
        int u = tid + 256 * i;
        int pq = u & 15, c2 = u >> 4;            // pq: p-quad 0..15, c2: 0..95
        int pp = m0 + pq * 4;
        int bb = (pp >= HW) ? 1 : 0;
        const float* src = x + ((size_t)(bb * CIN + c2 * 2)) * HW + (pp - bb * HW);
        float4 f0 = *(const float4*)src;          // c = c2*2,   p..p+3
        float4 f1 = *(const float4*)(src + HW);   // c = c2*2+1, p..p+3
        Asw[(pq * 4 + 0) * 100 + c2] = pack2(f0.x, f1.x);
        Asw[(pq * 4 + 1) * 100 + c2] = pack2(f0.y, f1.y);
        Asw[(pq * 4 + 2) * 100 + c2] = pack2(f0.z, f1.z);
        Asw[(pq * 4 + 3) * 100 + c2] = pack2(f0.w, f1.w);
    }
    {
        int o = tid >> 2, c4 = tid & 3;
        #pragma unroll
        for (int i = 0; i < 12; ++i) {
            int cq = c4 + 4 * i;                 // 0..47
            float4 w = *(const float4*)(Wp + (size_t)o * CIN + cq * 4);
            uint2 d; d.x = pack2(w.x, w.y); d.y = pack2(w.z, w.w);
            *(uint2*)(Bsw + o * 100 + cq * 2) = d;
        }
    }
    __syncthreads();

    f32x4 acc[2][2] = {};
    const unsigned short* pa0 = As + (wm + l15) * 200 + quad * 8;
    const unsigned short* pb0 = Bs + (wn + l15) * 200 + quad * 8;
    #pragma unroll
    for (int s = 0; s < 6; ++s) {
        short8 a0 = *(const short8*)(pa0 + s * 32);
        short8 a1 = *(const short8*)(pa0 + 16 * 200 + s * 32);
        short8 b0 = *(const short8*)(pb0 + s * 32);
        short8 b1 = *(const short8*)(pb0 + 16 * 200 + s * 32);
        acc[0][0] = __builtin_amdgcn_mfma_f32_16x16x32_bf16(a0, b0, acc[0][0], 0, 0, 0);
        acc[0][1] = __builtin_amdgcn_mfma_f32_16x16x32_bf16(a0, b1, acc[0][1], 0, 0, 0);
        acc[1][0] = __builtin_amdgcn_mfma_f32_16x16x32_bf16(a1, b0, acc[1][0], 0, 0, 0);
        acc[1][1] = __builtin_amdgcn_mfma_f32_16x16x32_bf16(a1, b1, acc[1][1], 0, 0, 0);
    }

    const int gm = m0 + wm + quad * 4;   // global pixel row
    const int gn = n0 + wn + l15;        // output channel (0..575)
    #pragma unroll
    for (int ti = 0; ti < 2; ++ti)
        #pragma unroll
        for (int tj = 0; tj < 2; ++tj)
            #pragma unroll
            for (int rr = 0; rr < 4; rr += 2) {
                unsigned r = pack2(acc[ti][tj][rr], acc[ti][tj][rr + 1]);
                qkv[(size_t)(gm + ti * 16 + rr) * QKVLD + (gn + tj * 16)] =
                    (unsigned short)r;
                qkv[(size_t)(gm + ti * 16 + rr + 1) * QKVLD + (gn + tj * 16)] =
                    (unsigned short)(r >> 16);
            }
}

// ======================= Phase 2: windowed attention ========================
// t in [0,588): 49 8x8-pixel tiles x 12 (b,h). 4 threads/pixel (d split 4x8).
// K and V staged bf16->fp32 into LDS (R6/R9 layout, stride 34 -- measured good).
__global__ __launch_bounds__(256) void k_p2(
    const unsigned short* __restrict__ qkv, const float* __restrict__ pos,
    unsigned short* __restrict__ oact)
{
    extern __shared__ char smem[];
    float* kbuf = (float*)smem;          // [196 px][32 ch] stride 34 floats
    float* vbuf = kbuf + 6664;

    const int tid = threadIdx.x;
    const int t = blockIdx.x;
    const int tz = t / 49, r49 = t - tz * 49;
    const int ty = r49 / 7, tx = r49 - ty * 7;
    const int bq = tz / 6, h = tz - bq * 6;
    const int y0 = ty * 8 - 3, x0 = tx * 8 - 3;

    // unified K+V staging: 1568 uint4 units = 196 px * (4 k + 4 v)
    #pragma unroll
    for (int i = 0; i < 7; ++i) {
        int u = tid + 256 * i;
        if (u < 1568) {
            int pp = u >> 3, uu = u & 7;
            int part = uu >> 2, sub8 = uu & 3;       // part 0=k, 1=v
            int py = pp / 14, px = pp - py * 14;
            int gy = y0 + py, gx = x0 + px;
            float f0=0,f1=0,f2=0,f3=0,f4=0,f5=0,f6=0,f7=0;
            if ((unsigned)gy < 56u && (unsigned)gx < 56u) {
                uint4 rv = *(const uint4*)(qkv +
                    (size_t)(bq * HW + gy * WIMG + gx) * QKVLD +
                    192 + part * 192 + h * 32 + sub8 * 8);
                f0=bflo(rv.x); f1=bfhi(rv.x); f2=bflo(rv.y); f3=bfhi(rv.y);
                f4=bflo(rv.z); f5=bfhi(rv.z); f6=bflo(rv.w); f7=bfhi(rv.w);
            }
            float* dst = (part ? vbuf : kbuf) + pp * 34 + sub8 * 8;
            *(float2*)(dst + 0) = make_float2(f0, f1);
            *(float2*)(dst + 2) = make_float2(f2, f3);
            *(float2*)(dst + 4) = make_float2(f4, f5);
            *(float2*)(dst + 6) = make_float2(f6, f7);
        }
    }
    __syncthreads();

    const int sub = tid & 3, pix = tid >> 2;
    const int py = pix >> 3, px = pix & 7;
    const int y = ty * 8 + py, xx = tx * 8 + px;
    const int p = y * WIMG + xx;

    uint4 qv = *(const uint4*)(qkv + (size_t)(bq * HW + p) * QKVLD + h * 32 + sub * 8);
    // R11b: fold log2e into q so logits live in the exp2 domain
    float q0=bflo(qv.x)*LOG2E, q1=bfhi(qv.x)*LOG2E;
    float q2=bflo(qv.y)*LOG2E, q3=bfhi(qv.y)*LOG2E;
    float q4=bflo(qv.z)*LOG2E, q5=bfhi(qv.z)*LOG2E;
    float q6=bflo(qv.w)*LOG2E, q7=bfhi(qv.w)*LOG2E;

    float posr[13];
    #pragma unroll
    for (int i = 0; i < 13; ++i) posr[i] = pos[i] * LOG2E;

    float logits[49];
    #pragma unroll
    for (int kk = 0; kk < 49; ++kk) {
        const int ky = kk / 7, kx = kk % 7;
        const int pp = (py + ky) * 14 + (px + kx);
        const float2* kp = (const float2*)(kbuf + pp * 34 + sub * 8);
        float2 k0 = kp[0], k1 = kp[1], k2 = kp[2], k3 = kp[3];
        float s = 0.f;
        s = fmaf(q0, k0.x, s); s = fmaf(q1, k0.y, s);
        s = fmaf(q2, k1.x, s); s = fmaf(q3, k1.y, s);
        s = fmaf(q4, k2.x, s); s = fmaf(q5, k2.y, s);
        s = fmaf(q6, k3.x, s); s = fmaf(q7, k3.y, s);
        logits[kk] = qsum4(s) + posr[ky + kx];   // DPP reduce (VALU pipe)
    }

    float m = logits[0];
    #pragma unroll
    for (int kk = 1; kk < 49; ++kk) m = fmaxf(m, logits[kk]);
    float sum = 0.f;
    #pragma unroll
    for (int kk = 0; kk < 49; ++kk) {
        logits[kk] = __builtin_amdgcn_exp2f(logits[kk] - m);   // R11b: direct exp2
        sum += logits[kk];
    }

    float a0=0,a1=0,a2=0,a3=0,a4=0,a5=0,a6=0,a7=0;
    #pragma unroll
    for (int kk = 0; kk < 49; ++kk) {
        const int ky = kk / 7, kx = kk % 7;
        const int pp = (py + ky) * 14 + (px + kx);
        const float2* vp = (const float2*)(vbuf + pp * 34 + sub * 8);
        float2 v0 = vp[0], v1 = vp[1], v2 = vp[2], v3 = vp[3];
        const float pw = logits[kk];             // inv deferred to epilogue
        a0 = fmaf(pw, v0.x, a0); a1 = fmaf(pw, v0.y, a1);
        a2 = fmaf(pw, v1.x, a2); a3 = fmaf(pw, v1.y, a3);
        a4 = fmaf(pw, v2.x, a4); a5 = fmaf(pw, v2.y, a5);
        a6 = fmaf(pw, v3.x, a6); a7 = fmaf(pw, v3.y, a7);
    }
    const float inv = 1.f / sum;

    uint4 o;
    o.x = pack2(a0 * inv, a1 * inv);
    o.y = pack2(a2 * inv, a3 * inv);
    o.z = pack2(a4 * inv, a5 * inv);
    o.w = pack2(a6 * inv, a7 * inv);
    *(uint4*)(oact + (size_t)(bq * HW + p) * CIN + h * 32 + sub * 8) = o;
}

// ======================= Phase 3: projection tile ===========================
// t in [0,294): mt = t%3 (64 out ch), pt = t/3 (64-pixel strip).
__global__ __launch_bounds__(256) void k_p3(
    const float* __restrict__ wproj, const unsigned short* __restrict__ oact,
    float* __restrict__ out)
{
    extern __shared__ char smem[];
    unsigned short* As  = (unsigned short*)smem;
    unsigned short* Bs  = As + 64 * 200;
    unsigned*       Asw = (unsigned*)smem;

    const int tid = threadIdx.x;
    const int lane = tid & 63, wave = tid >> 6;
    const int l15  = lane & 15, quad = lane >> 4;
    const int wm   = (wave & 1) * 32, wn = (wave >> 1) * 32;

    const int t = blockIdx.x;
    const int mt = t % 3, pt = t / 3;
    {
        int o = tid >> 2, c4 = tid & 3;
        #pragma unroll
        for (int i = 0; i < 12; ++i) {
            int cq = c4 + 4 * i;
            float4 w = *(const float4*)(wproj + (size_t)(mt * 64 + o) * CIN + cq * 4);
            uint2 d; d.x = pack2(w.x, w.y); d.y = pack2(w.z, w.w);
            *(uint2*)(Asw + o * 100 + cq * 2) = d;
        }
    }
    {
        int rw = tid >> 2, s4 = tid & 3;
        #pragma unroll
        for (int i = 0; i < 6; ++i) {
            int seg = s4 + 4 * i;               // 0..23
            uint4 dv = *(const uint4*)(oact + (size_t)(pt * 64 + rw) * CIN + seg * 8);
            *(uint4*)(Bs + rw * 200 + seg * 8) = dv;
        }
    }
    __syncthreads();

    f32x4 acc[2][2] = {};
    const unsigned short* pa0 = As + (wm + l15) * 200 + quad * 8;
    const unsigned short* pb0 = Bs + (wn + l15) * 200 + quad * 8;
    #pragma unroll
    for (int s = 0; s < 6; ++s) {
        short8 a0 = *(const short8*)(pa0 + s * 32);
        short8 a1 = *(const short8*)(pa0 + 16 * 200 + s * 32);
        short8 b0 = *(const short8*)(pb0 + s * 32);
        short8 b1 = *(const short8*)(pb0 + 16 * 200 + s * 32);
        acc[0][0] = __builtin_amdgcn_mfma_f32_16x16x32_bf16(a0, b0, acc[0][0], 0, 0, 0);
        acc[0][1] = __builtin_amdgcn_mfma_f32_16x16x32_bf16(a0, b1, acc[0][1], 0, 0, 0);
        acc[1][0] = __builtin_amdgcn_mfma_f32_16x16x32_bf16(a1, b0, acc[1][0], 0, 0, 0);
        acc[1][1] = __builtin_amdgcn_mfma_f32_16x16x32_bf16(a1, b1, acc[1][1], 0, 0, 0);
    }

    const int bb = (pt * 64 >= HW) ? 1 : 0;
    const int pl = pt * 64 - bb * HW + wn + l15;      // col = pixel within batch
    const int go = mt * 64 + wm + quad * 4;           // row = output channel
    float* Yb = out + (size_t)bb * (CIN * HW);
    #pragma unroll
    for (int ti = 0; ti < 2; ++ti)
        #pragma unroll
        for (int tj = 0; tj < 2; ++tj)
            #pragma unroll
            for (int rr = 0; rr < 4; ++rr)
                Yb[(size_t)(go + ti * 16 + rr) * HW + pl + tj * 16] = acc[ti][tj][rr];
}

// ---------------------------------------------------------------------------
extern "C" void kernel_launch(void* const* d_in, const int* in_sizes, int n_in,
                              void* d_out, int out_size, void* d_ws, size_t ws_size,
                              hipStream_t stream)
{
    const float* x     = (const float*)d_in[0];
    const float* wq    = (const float*)d_in[1];
    const float* wk    = (const float*)d_in[2];
    const float* wv    = (const float*)d_in[3];
    const float* pos   = (const float*)d_in[4];
    const float* wproj = (const float*)d_in[5];

    char* ws = (char*)d_ws;
    unsigned short* qkvp  = (unsigned short*)ws;
    unsigned short* oactp = (unsigned short*)(ws + 7225344);
    float*          outp  = (float*)d_out;

    k_p1<<<dim3(882), dim3(256), SMEM_BYTES, stream>>>(x, wq, wk, wv, qkvp);
    k_p2<<<dim3(588), dim3(256), SMEM_BYTES, stream>>>(qkvp, pos, oactp);
    k_p3<<<dim3(294), dim3(256), SMEM_BYTES, stream>>>(wproj, oactp, outp);
}

// Round 7
// 104.025 us; speedup vs baseline: 1.1494x; 1.0156x over previous
//
#include <hip/hip_runtime.h>

// SASA plain 3-kernel pipeline, R12: dot2-bf16 QK + pk_fma PV in phase-2.
// B=2, CIN=192, HW=3136, 6 heads x d=32, 7x7 window.
// Cost model: dur_us = kernels + ws-poison fills (2x256MiB @~43us = health gauge).
// History: R6=110.2 | R9=105.6 | R10 pixel-pair FAILED (+14, occupancy collapse,
//   lesson: keep >=2 waves/SIMD) | R11=105.6 on a ~2%-slower container (cvt_pk +
//   exp2 domain good for ~1.5-2us normalized).
// Pipe model: p2-fp32 dual-saturated: LDS ~3.9us (3136 B/thr @256B/clk/CU) and
// VALU ~3.8us (1500 instr x 3 waves/SIMD). R7/R8 bf16-LDS failed because unpack
// moved the wall to VALU. R12 shrinks BOTH pipes with no unpack:
//  (a) K stored as RAW bf16 (no unpack at stage or read); QK inner step =
//      1x ds_read_b128 + 4x v_dot2_f32_bf16 on packed K/Q pairs (Q stays the
//      raw uint4 from global). Products exact -> numerics = reorder only.
//      K stride 40 shorts (20 dw): analytically uniform 8 acc/bank/wave.
//  (b) V f32 stride 34 -> 36 (rows 144 B, 16B-aligned): float4 reads = 2x b128
//      guaranteed; v_pk_fma_f32 accumulation (4 pk + 1 mov vs 8 fma).
//      V read/write patterns uniform 8 acc/bank/wave.
//  (c) LOG2E folded post-reduce: fmaf(qsum4(s), LOG2E, pos*LOG2E) - free.
//  (d) Q/pos loads hoisted above staging (code motion only).
// LDS p2: 196*80 + 196*144 = 43,904 B -> still 3 blocks/CU (12 waves), regime kept.
// Per-kk: LDS 64->48 B (4->3 instr), VALU 21->14. Predict p2 ~4.5 -> ~3.4us.
//
// ws layout (bytes):
//   QKV  [6272][576] bf16 @ 0        q ch 0-191 | k 192-383 | v 384-575
//   OACT [6272][192] bf16 @ 7225344  attention out = proj B-operand

#define HW    3136
#define WIMG  56
#define CIN   192
#define QKVLD 576
#define SMEM_P1 53312
#define SMEM_P2 43904
#define LOG2E 1.44269504088896340736f

using short8 = __attribute__((ext_vector_type(8))) short;
using f32x4  = __attribute__((ext_vector_type(4))) float;

// packed RTNE f32x2 -> bf16x2, single HW instruction (lo = a, hi = b)
__device__ __forceinline__ unsigned pack2(float a, float b) {
    unsigned r;
    asm("v_cvt_pk_bf16_f32 %0, %1, %2" : "=v"(r) : "v"(a), "v"(b));
    return r;
}
__device__ __forceinline__ float bflo(unsigned u) {
    union { unsigned u; float f; } v; v.u = u << 16; return v.f;
}
__device__ __forceinline__ float bfhi(unsigned u) {
    union { unsigned u; float f; } v; v.u = u & 0xffff0000u; return v.f;
}
// D = S0.bf16[0]*S1.bf16[0] + S0.bf16[1]*S1.bf16[1] + S2   (exact products, f32 acc)
__device__ __forceinline__ float dot2bf(unsigned k2, unsigned q2, float c) {
    float d;
    asm("v_dot2_f32_bf16 %0, %1, %2, %3" : "=v"(d) : "v"(k2), "v"(q2), "v"(c));
    return d;
}
// packed dual f32 fma: d.lo = a.lo*b.lo + c.lo ; d.hi = a.hi*b.hi + c.hi
__device__ __forceinline__ float2 pkfma(float2 a, float2 b, float2 c) {
    float2 d;
    asm("v_pk_fma_f32 %0, %1, %2, %3" : "=v"(d) : "v"(a), "v"(b), "v"(c));
    return d;
}
// quad-of-4 butterfly sum via DPP quad_perm (VALU pipe, not ds_swizzle/LDS).
__device__ __forceinline__ float qsum4(float s) {
    union { float f; int i; } u, t;
    u.f = s;
    t.i = __builtin_amdgcn_update_dpp(0, u.i, 0xB1, 0xF, 0xF, true); // xor 1
    u.f += t.f;
    t.i = __builtin_amdgcn_update_dpp(0, u.i, 0x4E, 0xF, 0xF, true); // xor 2
    u.f += t.f;
    return u.f;
}

// ======================= Phase 1: QKV GEMM tile =============================
// t in [0,882): mt = t%98 (64-pixel strip over b,p), nt = t/98 (64 of 576 out ch).
__global__ __launch_bounds__(256) void k_p1(
    const float* __restrict__ x, const float* __restrict__ wq,
    const float* __restrict__ wk, const float* __restrict__ wv,
    unsigned short* __restrict__ qkv)
{
    extern __shared__ char smem[];
    unsigned short* As  = (unsigned short*)smem;     // 64 x 200 ushorts
    unsigned short* Bs  = As + 64 * 200;
    unsigned*       Asw = (unsigned*)smem;           // dword view, row stride 100
    unsigned*       Bsw = (unsigned*)(smem + 25600);

    const int tid = threadIdx.x;
    const int lane = tid & 63, wave = tid >> 6;
    const int l15  = lane & 15, quad = lane >> 4;
    const int wm   = (wave & 1) * 32, wn = (wave >> 1) * 32;

    const int t = blockIdx.x;
    const int mt = t % 98, nt = t / 98;
    const int m0 = mt * 64, n0 = nt * 64;
    const float* Wp = (nt < 3) ? (wq + (size_t)n0 * CIN)
                    : (nt < 6) ? (wk + (size_t)(n0 - 192) * CIN)
                               : (wv + (size_t)(n0 - 384) * CIN);

    #pragma unroll
    for (int i = 0; i < 6; ++i) {
        int u = tid + 256 * i;
        int pq = u & 15, c2 = u >> 4;            // pq: p-quad 0..15, c2: 0..95
        int pp = m0 + pq * 4;
        int bb = (pp >= HW) ? 1 : 0;
        const float* src = x + ((size_t)(bb * CIN + c2 * 2)) * HW + (pp - bb * HW);
        float4 f0 = *(const float4*)src;          // c = c2*2,   p..p+3
        float4 f1 = *(const float4*)(src + HW);   // c = c2*2+1, p..p+3
        Asw[(pq * 4 + 0) * 100 + c2] = pack2(f0.x, f1.x);
        Asw[(pq * 4 + 1) * 100 + c2] = pack2(f0.y, f1.y);
        Asw[(pq * 4 + 2) * 100 + c2] = pack2(f0.z, f1.z);
        Asw[(pq * 4 + 3) * 100 + c2] = pack2(f0.w, f1.w);
    }
    {
        int o = tid >> 2, c4 = tid & 3;
        #pragma unroll
        for (int i = 0; i < 12; ++i) {
            int cq = c4 + 4 * i;                 // 0..47
            float4 w = *(const float4*)(Wp + (size_t)o * CIN + cq * 4);
            uint2 d; d.x = pack2(w.x, w.y); d.y = pack2(w.z, w.w);
            *(uint2*)(Bsw + o * 100 + cq * 2) = d;
        }
    }
    __syncthreads();

    f32x4 acc[2][2] = {};
    const unsigned short* pa0 = As + (wm + l15) * 200 + quad * 8;
    const unsigned short* pb0 = Bs + (wn + l15) * 200 + quad * 8;
    #pragma unroll
    for (int s = 0; s < 6; ++s) {
        short8 a0 = *(const short8*)(pa0 + s * 32);
        short8 a1 = *(const short8*)(pa0 + 16 * 200 + s * 32);
        short8 b0 = *(const short8*)(pb0 + s * 32);
        short8 b1 = *(const short8*)(pb0 + 16 * 200 + s * 32);
        acc[0][0] = __builtin_amdgcn_mfma_f32_16x16x32_bf16(a0, b0, acc[0][0], 0, 0, 0);
        acc[0][1] = __builtin_amdgcn_mfma_f32_16x16x32_bf16(a0, b1, acc[0][1], 0, 0, 0);
        acc[1][0] = __builtin_amdgcn_mfma_f32_16x16x32_bf16(a1, b0, acc[1][0], 0, 0, 0);
        acc[1][1] = __builtin_amdgcn_mfma_f32_16x16x32_bf16(a1, b1, acc[1][1], 0, 0, 0);
    }

    const int gm = m0 + wm + quad * 4;   // global pixel row
    const int gn = n0 + wn + l15;        // output channel (0..575)
    #pragma unroll
    for (int ti = 0; ti < 2; ++ti)
        #pragma unroll
        for (int tj = 0; tj < 2; ++tj)
            #pragma unroll
            for (int rr = 0; rr < 4; rr += 2) {
                unsigned r = pack2(acc[ti][tj][rr], acc[ti][tj][rr + 1]);
                qkv[(size_t)(gm + ti * 16 + rr) * QKVLD + (gn + tj * 16)] =
                    (unsigned short)r;
                qkv[(size_t)(gm + ti * 16 + rr + 1) * QKVLD + (gn + tj * 16)] =
                    (unsigned short)(r >> 16);
            }
}

// ======================= Phase 2: windowed attention ========================
// t in [0,588): 49 8x8-pixel tiles x 12 (b,h). 4 threads/pixel (d split 4x8).
// K raw bf16 in LDS (stride 40 shorts), consumed by v_dot2_f32_bf16.
// V f32 in LDS (stride 36 floats), consumed by v_pk_fma_f32.
__global__ __launch_bounds__(256) void k_p2(
    const unsigned short* __restrict__ qkv, const float* __restrict__ pos,
    unsigned short* __restrict__ oact)
{
    extern __shared__ char smem[];
    unsigned short* kbufB = (unsigned short*)smem;      // [196 px][32 ch] stride 40
    float*          vbuf  = (float*)(smem + 196 * 40 * 2); // [196 px][32 ch] stride 36

    const int tid = threadIdx.x;
    const int t = blockIdx.x;
    const int tz = t / 49, r49 = t - tz * 49;
    const int ty = r49 / 7, tx = r49 - ty * 7;
    const int bq = tz / 6, h = tz - bq * 6;
    const int y0 = ty * 8 - 3, x0 = tx * 8 - 3;

    const int sub = tid & 3, pix = tid >> 2;
    const int py = pix >> 3, px = pix & 7;
    const int y = ty * 8 + py, xx = tx * 8 + px;
    const int p = y * WIMG + xx;

    // R12d: Q (raw packed bf16) + pos hoisted above staging
    uint4 qv = *(const uint4*)(qkv + (size_t)(bq * HW + p) * QKVLD + h * 32 + sub * 8);
    float posE[13];
    #pragma unroll
    for (int i = 0; i < 13; ++i) posE[i] = pos[i] * LOG2E;

    // unified K+V staging: 1568 uint4 units = 196 px * (4 k + 4 v)
    #pragma unroll
    for (int i = 0; i < 7; ++i) {
        int u = tid + 256 * i;
        if (u < 1568) {
            int pp = u >> 3, uu = u & 7;
            int part = uu >> 2, sub8 = uu & 3;       // part 0=k, 1=v
            int ppy = pp / 14, ppx = pp - ppy * 14;
            int gy = y0 + ppy, gx = x0 + ppx;
            uint4 rv = make_uint4(0u, 0u, 0u, 0u);
            if ((unsigned)gy < 56u && (unsigned)gx < 56u)
                rv = *(const uint4*)(qkv +
                    (size_t)(bq * HW + gy * WIMG + gx) * QKVLD +
                    192 + part * 192 + h * 32 + sub8 * 8);
            if (part == 0) {
                // K: raw bf16 copy, no unpack
                *(uint4*)(kbufB + pp * 40 + sub8 * 8) = rv;
            } else {
                // V: unpack to f32, stride 36 (16B-aligned rows)
                float4 vA, vB;
                vA.x=bflo(rv.x); vA.y=bfhi(rv.x); vA.z=bflo(rv.y); vA.w=bfhi(rv.y);
                vB.x=bflo(rv.z); vB.y=bfhi(rv.z); vB.z=bflo(rv.w); vB.w=bfhi(rv.w);
                float* dst = vbuf + pp * 36 + sub8 * 8;
                *(float4*)(dst + 0) = vA;
                *(float4*)(dst + 4) = vB;
            }
        }
    }
    __syncthreads();

    const unsigned short* kr = kbufB + sub * 8;

    float logits[49];
    #pragma unroll
    for (int kk = 0; kk < 49; ++kk) {
        const int ky = kk / 7, kx = kk % 7;
        const int pp = (py + ky) * 14 + (px + kx);
        uint4 kv = *(const uint4*)(kr + pp * 40);
        float s = 0.f;
        s = dot2bf(kv.x, qv.x, s);
        s = dot2bf(kv.y, qv.y, s);
        s = dot2bf(kv.z, qv.z, s);
        s = dot2bf(kv.w, qv.w, s);
        // R12c: natural-log dot scaled into exp2 domain, pos pre-scaled
        logits[kk] = fmaf(qsum4(s), LOG2E, posE[ky + kx]);
    }

    float m = logits[0];
    #pragma unroll
    for (int kk = 1; kk < 49; ++kk) m = fmaxf(m, logits[kk]);
    float sum = 0.f;
    #pragma unroll
    for (int kk = 0; kk < 49; ++kk) {
        logits[kk] = __builtin_amdgcn_exp2f(logits[kk] - m);
        sum += logits[kk];
    }

    float2 a01 = make_float2(0.f, 0.f), a23 = make_float2(0.f, 0.f);
    float2 a45 = make_float2(0.f, 0.f), a67 = make_float2(0.f, 0.f);
    #pragma unroll
    for (int kk = 0; kk < 49; ++kk) {
        const int ky = kk / 7, kx = kk % 7;
        const int pp = (py + ky) * 14 + (px + kx);
        const float4* vp = (const float4*)(vbuf + pp * 36 + sub * 8);
        float4 vA = vp[0], vB = vp[1];
        const float pw = logits[kk];
        const float2 pw2 = make_float2(pw, pw);
        a01 = pkfma(make_float2(vA.x, vA.y), pw2, a01);
        a23 = pkfma(make_float2(vA.z, vA.w), pw2, a23);
        a45 = pkfma(make_float2(vB.x, vB.y), pw2, a45);
        a67 = pkfma(make_float2(vB.z, vB.w), pw2, a67);
    }
    const float inv = 1.f / sum;

    uint4 o;
    o.x = pack2(a01.x * inv, a01.y * inv);
    o.y = pack2(a23.x * inv, a23.y * inv);
    o.z = pack2(a45.x * inv, a45.y * inv);
    o.w = pack2(a67.x * inv, a67.y * inv);
    *(uint4*)(oact + (size_t)(bq * HW + p) * CIN + h * 32 + sub * 8) = o;
}

// ======================= Phase 3: projection tile ===========================
// t in [0,294): mt = t%3 (64 out ch), pt = t/3 (64-pixel strip).
__global__ __launch_bounds__(256) void k_p3(
    const float* __restrict__ wproj, const unsigned short* __restrict__ oact,
    float* __restrict__ out)
{
    extern __shared__ char smem[];
    unsigned short* As  = (unsigned short*)smem;
    unsigned short* Bs  = As + 64 * 200;
    unsigned*       Asw = (unsigned*)smem;

    const int tid = threadIdx.x;
    const int lane = tid & 63, wave = tid >> 6;
    const int l15  = lane & 15, quad = lane >> 4;
    const int wm   = (wave & 1) * 32, wn = (wave >> 1) * 32;

    const int t = blockIdx.x;
    const int mt = t % 3, pt = t / 3;
    {
        int o = tid >> 2, c4 = tid & 3;
        #pragma unroll
        for (int i = 0; i < 12; ++i) {
            int cq = c4 + 4 * i;
            float4 w = *(const float4*)(wproj + (size_t)(mt * 64 + o) * CIN + cq * 4);
            uint2 d; d.x = pack2(w.x, w.y); d.y = pack2(w.z, w.w);
            *(uint2*)(Asw + o * 100 + cq * 2) = d;
        }
    }
    {
        int rw = tid >> 2, s4 = tid & 3;
        #pragma unroll
        for (int i = 0; i < 6; ++i) {
            int seg = s4 + 4 * i;               // 0..23
            uint4 dv = *(const uint4*)(oact + (size_t)(pt * 64 + rw) * CIN + seg * 8);
            *(uint4*)(Bs + rw * 200 + seg * 8) = dv;
        }
    }
    __syncthreads();

    f32x4 acc[2][2] = {};
    const unsigned short* pa0 = As + (wm + l15) * 200 + quad * 8;
    const unsigned short* pb0 = Bs + (wn + l15) * 200 + quad * 8;
    #pragma unroll
    for (int s = 0; s < 6; ++s) {
        short8 a0 = *(const short8*)(pa0 + s * 32);
        short8 a1 = *(const short8*)(pa0 + 16 * 200 + s * 32);
        short8 b0 = *(const short8*)(pb0 + s * 32);
        short8 b1 = *(const short8*)(pb0 + 16 * 200 + s * 32);
        acc[0][0] = __builtin_amdgcn_mfma_f32_16x16x32_bf16(a0, b0, acc[0][0], 0, 0, 0);
        acc[0][1] = __builtin_amdgcn_mfma_f32_16x16x32_bf16(a0, b1, acc[0][1], 0, 0, 0);
        acc[1][0] = __builtin_amdgcn_mfma_f32_16x16x32_bf16(a1, b0, acc[1][0], 0, 0, 0);
        acc[1][1] = __builtin_amdgcn_mfma_f32_16x16x32_bf16(a1, b1, acc[1][1], 0, 0, 0);
    }

    const int bb = (pt * 64 >= HW) ? 1 : 0;
    const int pl = pt * 64 - bb * HW + wn + l15;      // col = pixel within batch
    const int go = mt * 64 + wm + quad * 4;           // row = output channel
    float* Yb = out + (size_t)bb * (CIN * HW);
    #pragma unroll
    for (int ti = 0; ti < 2; ++ti)
        #pragma unroll
        for (int tj = 0; tj < 2; ++tj)
            #pragma unroll
            for (int rr = 0; rr < 4; ++rr)
                Yb[(size_t)(go + ti * 16 + rr) * HW + pl + tj * 16] = acc[ti][tj][rr];
}

// ---------------------------------------------------------------------------
extern "C" void kernel_launch(void* const* d_in, const int* in_sizes, int n_in,
                              void* d_out, int out_size, void* d_ws, size_t ws_size,
                              hipStream_t stream)
{
    const float* x     = (const float*)d_in[0];
    const float* wq    = (const float*)d_in[1];
    const float* wk    = (const float*)d_in[2];
    const float* wv    = (const float*)d_in[3];
    const float* pos   = (const float*)d_in[4];
    const float* wproj = (const float*)d_in[5];

    char* ws = (char*)d_ws;
    unsigned short* qkvp  = (unsigned short*)ws;
    unsigned short* oactp = (unsigned short*)(ws + 7225344);
    float*          outp  = (float*)d_out;

    k_p1<<<dim3(882), dim3(256), SMEM_P1, stream>>>(x, wq, wk, wv, qkvp);
    k_p2<<<dim3(588), dim3(256), SMEM_P2, stream>>>(qkvp, pos, oactp);
    k_p3<<<dim3(294), dim3(256), SMEM_P1, stream>>>(wproj, oactp, outp);
}